// Round 4
// baseline (1664.846 us; speedup 1.0000x reference)
//
#include <hip/hip_runtime.h>

#define N_NODES 50000
#define N_EDGES 600000
#define IN_DIM 9
#define HID 128
#define OUT_DIM 6
#define NPB 8                                   // dst nodes per fused block
#define EPB 16                                  // edges per chunk
#define SCAN_BLKS ((N_NODES + 255) / 256)       // 196

// ---------------------------------------------------------------------------
// Kernel A: node encoder  h_v = relu(x @ W1 + b1) @ W2 + b2     [N,9] -> [N,128]
// ---------------------------------------------------------------------------
__global__ __launch_bounds__(128)
void node_encoder(const float* __restrict__ x,
                  const float* __restrict__ W1,   // [9,128]
                  const float* __restrict__ b1,
                  const float* __restrict__ W2,   // [128,128]
                  const float* __restrict__ b2,
                  float* __restrict__ hv)         // [N,128]
{
    const int t  = threadIdx.x;
    const int n0 = blockIdx.x * 4;

    __shared__ float xs[4][12];
    __shared__ float h1[4][132];

    if (t < 4 * IN_DIM) {
        int n = t / IN_DIM, k = t % IN_DIM;
        xs[n][k] = x[(n0 + n) * IN_DIM + k];
    }
    __syncthreads();

    float w[IN_DIM];
#pragma unroll
    for (int k = 0; k < IN_DIM; ++k) w[k] = W1[k * HID + t];
    const float bb1 = b1[t];
#pragma unroll
    for (int n = 0; n < 4; ++n) {
        float s = bb1;
#pragma unroll
        for (int k = 0; k < IN_DIM; ++k) s += xs[n][k] * w[k];
        h1[n][t] = fmaxf(s, 0.f);
    }
    __syncthreads();

    float acc[4] = {0.f, 0.f, 0.f, 0.f};
    for (int k = 0; k < HID; k += 4) {
        const float w0 = W2[(k + 0) * HID + t];
        const float w1 = W2[(k + 1) * HID + t];
        const float w2 = W2[(k + 2) * HID + t];
        const float w3 = W2[(k + 3) * HID + t];
#pragma unroll
        for (int n = 0; n < 4; ++n) {
            const float4 a = *(const float4*)&h1[n][k];
            acc[n] += a.x * w0 + a.y * w1 + a.z * w2 + a.w * w3;
        }
    }
    const float bb2 = b2[t];
#pragma unroll
    for (int n = 0; n < 4; ++n)
        hv[(size_t)(n0 + n) * HID + t] = acc[n] + bb2;
}

// ---------------------------------------------------------------------------
// CSR build: count -> exclusive scan -> fill   (col -> list of edge ids)
// ---------------------------------------------------------------------------
__global__ __launch_bounds__(256)
void csr_count(const int* __restrict__ col, int* __restrict__ cnt) {
    const int i = blockIdx.x * 256 + threadIdx.x;
    if (i < N_EDGES) atomicAdd(&cnt[col[i]], 1);
}

__global__ __launch_bounds__(256)
void scan_part(const int* __restrict__ cnt, int* __restrict__ part) {
    __shared__ int s[256];
    const int tid = threadIdx.x;
    const int i = blockIdx.x * 256 + tid;
    s[tid] = (i < N_NODES) ? cnt[i] : 0;
    __syncthreads();
#pragma unroll
    for (int off = 128; off > 0; off >>= 1) {
        if (tid < off) s[tid] += s[tid + off];
        __syncthreads();
    }
    if (tid == 0) part[blockIdx.x] = s[0];
}

__global__ __launch_bounds__(256)
void scan_scan(int* __restrict__ part) {     // exclusive scan of SCAN_BLKS entries
    __shared__ int s[256];
    const int tid = threadIdx.x;
    const int v = (tid < SCAN_BLKS) ? part[tid] : 0;
    s[tid] = v;
    __syncthreads();
    for (int off = 1; off < 256; off <<= 1) {
        int x = (tid >= off) ? s[tid - off] : 0;
        __syncthreads();
        s[tid] += x;
        __syncthreads();
    }
    part[tid] = s[tid] - v;   // exclusive
}

__global__ __launch_bounds__(256)
void scan_final(const int* __restrict__ cnt, const int* __restrict__ part,
                int* __restrict__ ofs, int* __restrict__ cursor) {
    __shared__ int s[256];
    const int tid = threadIdx.x;
    const int i = blockIdx.x * 256 + tid;
    const int v = (i < N_NODES) ? cnt[i] : 0;
    s[tid] = v;
    __syncthreads();
    for (int off = 1; off < 256; off <<= 1) {
        int x = (tid >= off) ? s[tid - off] : 0;
        __syncthreads();
        s[tid] += x;
        __syncthreads();
    }
    const int excl = part[blockIdx.x] + s[tid] - v;
    if (i <= N_NODES) ofs[i] = excl;          // ofs[N_NODES] lands = N_EDGES
    if (i <  N_NODES) cursor[i] = excl;
}

__global__ __launch_bounds__(256)
void csr_fill(const int* __restrict__ col, int* __restrict__ cursor,
              int* __restrict__ eid) {
    const int i = blockIdx.x * 256 + threadIdx.x;
    if (i < N_EDGES) {
        const int p = atomicAdd(&cursor[col[i]], 1);
        eid[p] = i;
    }
}

// ---------------------------------------------------------------------------
// Fused kernel: per 8 dst nodes — edge MLP over incoming edges, LDS-accumulate,
// then node-update MLP -> d_out.  NO global atomics, no h_e/agg buffers.
// 128 threads. Edge compute: thread = (edge-group of 4) x (col-group of 4).
// ---------------------------------------------------------------------------
__global__ __launch_bounds__(128)
void fused_edge_agg_update(const float* __restrict__ hv,
                           const int* __restrict__ row,
                           const int* __restrict__ col,
                           const float* __restrict__ eattr,
                           const int* __restrict__ ofs,
                           const int* __restrict__ eid,
                           const float* __restrict__ eeW1,  // [257,128]
                           const float* __restrict__ eeb1,
                           const float* __restrict__ eeW2,  // [128,128]
                           const float* __restrict__ eeb2,
                           const float* __restrict__ nuW1,  // [256,128]
                           const float* __restrict__ nub1,
                           const float* __restrict__ nuW2,  // [128,6]
                           const float* __restrict__ nub2,
                           float* __restrict__ out)         // [N,6]
{
    const int tid = threadIdx.x;
    const int n0  = blockIdx.x * NPB;

    __shared__ float ins[EPB][260];      // gather buffer; h1s overlays it later
    __shared__ float aggs[NPB][132];     // per-node message accumulator
    __shared__ int   er[EPB], ec[EPB], ed[EPB];
    __shared__ float part[NPB][2][OUT_DIM];

    for (int i = tid; i < NPB * 132; i += 128) (&aggs[0][0])[i] = 0.f;

    const int estart = ofs[n0];
    const int eend   = ofs[n0 + NPB];

    const int cg = tid & 31;
    const int eg = tid >> 5;
    const int c0 = cg * 4;
    const int eb = eg * 4;

    for (int base = estart; base < eend; base += EPB) {
        __syncthreads();   // prev iter's h1s reads done before ins/meta rewrite

        if (tid < EPB) {
            const int valid = (base + tid) < eend;
            const int e = eid[valid ? (base + tid) : base];
            er[tid] = row[e];
            const int c = col[e];
            ec[tid] = c;
            ed[tid] = valid ? (c - n0) : -1;
            ins[tid][256] = eattr[e];
        }
        __syncthreads();

        // vectorized gather: 16 edges x 2 endpoints x 32 float4-chunks
#pragma unroll
        for (int i = tid; i < EPB * 2 * 32; i += 128) {
            const int chunk = i & 31;
            const int src   = (i >> 5) & 1;
            const int e     = i >> 6;
            const int node  = src ? ec[e] : er[e];
            const float4 v = *(const float4*)&hv[(size_t)node * HID + chunk * 4];
            *(float4*)&ins[e][src * HID + chunk * 4] = v;
        }
        __syncthreads();

        // ---- edge layer 1 ----
        float acc[4][4];
#pragma unroll
        for (int e = 0; e < 4; ++e)
#pragma unroll
            for (int c = 0; c < 4; ++c) acc[e][c] = 0.f;

        for (int k = 0; k < 2 * HID; k += 4) {
            float4 wr0 = *(const float4*)&eeW1[(k + 0) * HID + c0];
            float4 wr1 = *(const float4*)&eeW1[(k + 1) * HID + c0];
            float4 wr2 = *(const float4*)&eeW1[(k + 2) * HID + c0];
            float4 wr3 = *(const float4*)&eeW1[(k + 3) * HID + c0];
#pragma unroll
            for (int e = 0; e < 4; ++e) {
                const float4 a = *(const float4*)&ins[eb + e][k];
                acc[e][0] += a.x * wr0.x + a.y * wr1.x + a.z * wr2.x + a.w * wr3.x;
                acc[e][1] += a.x * wr0.y + a.y * wr1.y + a.z * wr2.y + a.w * wr3.y;
                acc[e][2] += a.x * wr0.z + a.y * wr1.z + a.z * wr2.z + a.w * wr3.z;
                acc[e][3] += a.x * wr0.w + a.y * wr1.w + a.z * wr2.w + a.w * wr3.w;
            }
        }
        {   // attr row (k = 256)
            const float4 wa = *(const float4*)&eeW1[256 * HID + c0];
#pragma unroll
            for (int e = 0; e < 4; ++e) {
                const float a = ins[eb + e][256];
                acc[e][0] += a * wa.x; acc[e][1] += a * wa.y;
                acc[e][2] += a * wa.z; acc[e][3] += a * wa.w;
            }
        }

        __syncthreads();   // ins dead; overlay h1s
        float (*h1s)[132] = (float (*)[132])&ins[0][0];
        {
            const float4 bb = *(const float4*)&eeb1[c0];
#pragma unroll
            for (int e = 0; e < 4; ++e) {
                h1s[eb + e][c0 + 0] = fmaxf(acc[e][0] + bb.x, 0.f);
                h1s[eb + e][c0 + 1] = fmaxf(acc[e][1] + bb.y, 0.f);
                h1s[eb + e][c0 + 2] = fmaxf(acc[e][2] + bb.z, 0.f);
                h1s[eb + e][c0 + 3] = fmaxf(acc[e][3] + bb.w, 0.f);
            }
        }
        __syncthreads();

        // ---- edge layer 2 ----
        float acc2[4][4];
#pragma unroll
        for (int e = 0; e < 4; ++e)
#pragma unroll
            for (int c = 0; c < 4; ++c) acc2[e][c] = 0.f;

        for (int k = 0; k < HID; k += 4) {
            float4 wr0 = *(const float4*)&eeW2[(k + 0) * HID + c0];
            float4 wr1 = *(const float4*)&eeW2[(k + 1) * HID + c0];
            float4 wr2 = *(const float4*)&eeW2[(k + 2) * HID + c0];
            float4 wr3 = *(const float4*)&eeW2[(k + 3) * HID + c0];
#pragma unroll
            for (int e = 0; e < 4; ++e) {
                const float4 a = *(const float4*)&h1s[eb + e][k];
                acc2[e][0] += a.x * wr0.x + a.y * wr1.x + a.z * wr2.x + a.w * wr3.x;
                acc2[e][1] += a.x * wr0.y + a.y * wr1.y + a.z * wr2.y + a.w * wr3.y;
                acc2[e][2] += a.x * wr0.z + a.y * wr1.z + a.z * wr2.z + a.w * wr3.z;
                acc2[e][3] += a.x * wr0.w + a.y * wr1.w + a.z * wr2.w + a.w * wr3.w;
            }
        }

        // ---- accumulate into LDS agg tile (ds_add_f32, no return) ----
        const float4 bb2 = *(const float4*)&eeb2[c0];
#pragma unroll
        for (int e = 0; e < 4; ++e) {
            const int d = ed[eb + e];
            if (d >= 0) {
                atomicAdd(&aggs[d][c0 + 0], acc2[e][0] + bb2.x);
                atomicAdd(&aggs[d][c0 + 1], acc2[e][1] + bb2.y);
                atomicAdd(&aggs[d][c0 + 2], acc2[e][2] + bb2.z);
                atomicAdd(&aggs[d][c0 + 3], acc2[e][3] + bb2.w);
            }
        }
    }
    __syncthreads();   // agg complete; ins region free

    // ---- node update: relu([hv, agg] @ nuW1 + nub1) @ nuW2 + nub2 ----
    float (*hvs)[132] = (float (*)[132])&ins[0][0];            // 8x132 floats
    float* h1u = &ins[0][0] + NPB * 132;                       // 8x132 floats

    for (int i = tid; i < NPB * 32; i += 128) {                // 8 rows x 32 float4
        const int n = i >> 5, chunk = i & 31;
        *(float4*)&hvs[n][chunk * 4] =
            *(const float4*)&hv[(size_t)(n0 + n) * HID + chunk * 4];
    }
    __syncthreads();

    const int t = tid;   // output column 0..127
    float acc[NPB];
#pragma unroll
    for (int n = 0; n < NPB; ++n) acc[n] = 0.f;

    for (int k = 0; k < HID; k += 4) {
        const float w0 = nuW1[(k + 0) * HID + t];
        const float w1 = nuW1[(k + 1) * HID + t];
        const float w2 = nuW1[(k + 2) * HID + t];
        const float w3 = nuW1[(k + 3) * HID + t];
#pragma unroll
        for (int n = 0; n < NPB; ++n) {
            const float4 a = *(const float4*)&hvs[n][k];
            acc[n] += a.x * w0 + a.y * w1 + a.z * w2 + a.w * w3;
        }
    }
    for (int k = 0; k < HID; k += 4) {
        const float w0 = nuW1[(HID + k + 0) * HID + t];
        const float w1 = nuW1[(HID + k + 1) * HID + t];
        const float w2 = nuW1[(HID + k + 2) * HID + t];
        const float w3 = nuW1[(HID + k + 3) * HID + t];
#pragma unroll
        for (int n = 0; n < NPB; ++n) {
            const float4 a = *(const float4*)&aggs[n][k];
            acc[n] += a.x * w0 + a.y * w1 + a.z * w2 + a.w * w3;
        }
    }
    const float bb1 = nub1[t];
#pragma unroll
    for (int n = 0; n < NPB; ++n) h1u[n * 132 + t] = fmaxf(acc[n] + bb1, 0.f);
    __syncthreads();

    float wv[OUT_DIM];
#pragma unroll
    for (int j = 0; j < OUT_DIM; ++j) wv[j] = nuW2[t * OUT_DIM + j];

#pragma unroll
    for (int n = 0; n < NPB; ++n) {
        const float v = h1u[n * 132 + t];
        float p[OUT_DIM];
#pragma unroll
        for (int j = 0; j < OUT_DIM; ++j) p[j] = v * wv[j];
#pragma unroll
        for (int off = 32; off > 0; off >>= 1) {
#pragma unroll
            for (int j = 0; j < OUT_DIM; ++j) p[j] += __shfl_down(p[j], off);
        }
        if ((t & 63) == 0) {
#pragma unroll
            for (int j = 0; j < OUT_DIM; ++j) part[n][t >> 6][j] = p[j];
        }
    }
    __syncthreads();

    if (tid < NPB * OUT_DIM) {
        const int n = tid / OUT_DIM, j = tid % OUT_DIM;
        out[(size_t)(n0 + n) * OUT_DIM + j] = part[n][0][j] + part[n][1][j] + nub2[j];
    }
}

// ---------------------------------------------------------------------------
extern "C" void kernel_launch(void* const* d_in, const int* in_sizes, int n_in,
                              void* d_out, int out_size, void* d_ws, size_t ws_size,
                              hipStream_t stream) {
    const float* node_states = (const float*)d_in[0];
    const int*   edge_index  = (const int*)d_in[1];   // [2, E] int32
    const float* edge_attr   = (const float*)d_in[2];
    const float* ne_W1 = (const float*)d_in[3];
    const float* ne_b1 = (const float*)d_in[4];
    const float* ne_W2 = (const float*)d_in[5];
    const float* ne_b2 = (const float*)d_in[6];
    const float* ee_W1 = (const float*)d_in[7];
    const float* ee_b1 = (const float*)d_in[8];
    const float* ee_W2 = (const float*)d_in[9];
    const float* ee_b2 = (const float*)d_in[10];
    const float* nu_W1 = (const float*)d_in[11];
    const float* nu_b1 = (const float*)d_in[12];
    const float* nu_W2 = (const float*)d_in[13];
    const float* nu_b2 = (const float*)d_in[14];

    const int* row = edge_index;
    const int* col = edge_index + N_EDGES;

    // workspace layout (≈ 28.6 MB)
    float* hv     = (float*)d_ws;                       // [N,128]
    int*   cnt    = (int*)(hv + (size_t)N_NODES * HID); // [N]
    int*   ofs    = cnt + N_NODES;                      // [N+1]
    int*   cursor = ofs + (N_NODES + 1);                // [N]
    int*   part   = cursor + N_NODES;                   // [256]
    int*   eids   = part + 256;                         // [E]

    hipMemsetAsync(cnt, 0, N_NODES * sizeof(int), stream);

    node_encoder<<<N_NODES / 4, 128, 0, stream>>>(
        node_states, ne_W1, ne_b1, ne_W2, ne_b2, hv);

    csr_count<<<(N_EDGES + 255) / 256, 256, 0, stream>>>(col, cnt);
    scan_part<<<SCAN_BLKS, 256, 0, stream>>>(cnt, part);
    scan_scan<<<1, 256, 0, stream>>>(part);
    scan_final<<<SCAN_BLKS, 256, 0, stream>>>(cnt, part, ofs, cursor);
    csr_fill<<<(N_EDGES + 255) / 256, 256, 0, stream>>>(col, cursor, eids);

    fused_edge_agg_update<<<N_NODES / NPB, 128, 0, stream>>>(
        hv, row, col, edge_attr, ofs, eids,
        ee_W1, ee_b1, ee_W2, ee_b2,
        nu_W1, nu_b1, nu_W2, nu_b2, (float*)d_out);
}

// Round 7
// 721.243 us; speedup vs baseline: 2.3083x; 2.3083x over previous
//
#include <hip/hip_runtime.h>

#define N_NODES 50000
#define N_EDGES 600000
#define IN_DIM 9
#define HID 128
#define OUT_DIM 6
#define SCAN_BLKS ((N_NODES + 255) / 256)   // 196

typedef __attribute__((ext_vector_type(8))) short short8;
typedef __attribute__((ext_vector_type(4))) float f32x4;

// split x = hi + lo (bf16 each); hi is RNE, lo is truncated residual.
__device__ __forceinline__ void split_bf16(float x, ushort& hi, ushort& lo) {
    unsigned u = __float_as_uint(x);
    unsigned r = u + 0x7FFF + ((u >> 16) & 1);
    hi = (ushort)(r >> 16);
    float hif = __uint_as_float((unsigned)hi << 16);
    lo = (ushort)(__float_as_uint(x - hif) >> 16);
}

// ---------------------------------------------------------------------------
// Kernel A: node encoder  h_v = relu(x @ W1 + b1) @ W2 + b2   [N,9]->[N,128]
// (verbatim from measured-correct round 3)
// ---------------------------------------------------------------------------
__global__ __launch_bounds__(128)
void node_encoder(const float* __restrict__ x,
                  const float* __restrict__ W1, const float* __restrict__ b1,
                  const float* __restrict__ W2, const float* __restrict__ b2,
                  float* __restrict__ hv)
{
    const int t  = threadIdx.x;
    const int n0 = blockIdx.x * 4;

    __shared__ float xs[4][12];
    __shared__ float h1[4][132];

    if (t < 4 * IN_DIM) {
        int n = t / IN_DIM, k = t % IN_DIM;
        xs[n][k] = x[(n0 + n) * IN_DIM + k];
    }
    __syncthreads();

    float w[IN_DIM];
#pragma unroll
    for (int k = 0; k < IN_DIM; ++k) w[k] = W1[k * HID + t];
    const float bb1 = b1[t];
#pragma unroll
    for (int n = 0; n < 4; ++n) {
        float s = bb1;
#pragma unroll
        for (int k = 0; k < IN_DIM; ++k) s += xs[n][k] * w[k];
        h1[n][t] = fmaxf(s, 0.f);
    }
    __syncthreads();

    float acc[4] = {0.f, 0.f, 0.f, 0.f};
    for (int k = 0; k < HID; k += 4) {
        const float w0 = W2[(k + 0) * HID + t];
        const float w1 = W2[(k + 1) * HID + t];
        const float w2 = W2[(k + 2) * HID + t];
        const float w3 = W2[(k + 3) * HID + t];
#pragma unroll
        for (int n = 0; n < 4; ++n) {
            const float4 a = *(const float4*)&h1[n][k];
            acc[n] += a.x * w0 + a.y * w1 + a.z * w2 + a.w * w3;
        }
    }
    const float bb2 = b2[t];
#pragma unroll
    for (int n = 0; n < 4; ++n)
        hv[(size_t)(n0 + n) * HID + t] = acc[n] + bb2;
}

// ---------------------------------------------------------------------------
// CSR build (verbatim from measured-correct round 4): col -> edge list
// ---------------------------------------------------------------------------
__global__ __launch_bounds__(256)
void csr_count(const int* __restrict__ col, int* __restrict__ cnt) {
    const int i = blockIdx.x * 256 + threadIdx.x;
    if (i < N_EDGES) atomicAdd(&cnt[col[i]], 1);
}

__global__ __launch_bounds__(256)
void scan_part(const int* __restrict__ cnt, int* __restrict__ part) {
    __shared__ int s[256];
    const int tid = threadIdx.x;
    const int i = blockIdx.x * 256 + tid;
    s[tid] = (i < N_NODES) ? cnt[i] : 0;
    __syncthreads();
#pragma unroll
    for (int off = 128; off > 0; off >>= 1) {
        if (tid < off) s[tid] += s[tid + off];
        __syncthreads();
    }
    if (tid == 0) part[blockIdx.x] = s[0];
}

__global__ __launch_bounds__(256)
void scan_scan(int* __restrict__ part) {
    __shared__ int s[256];
    const int tid = threadIdx.x;
    const int v = (tid < SCAN_BLKS) ? part[tid] : 0;
    s[tid] = v;
    __syncthreads();
    for (int off = 1; off < 256; off <<= 1) {
        int x = (tid >= off) ? s[tid - off] : 0;
        __syncthreads();
        s[tid] += x;
        __syncthreads();
    }
    part[tid] = s[tid] - v;
}

__global__ __launch_bounds__(256)
void scan_final(const int* __restrict__ cnt, const int* __restrict__ part,
                int* __restrict__ ofs, int* __restrict__ cursor) {
    __shared__ int s[256];
    const int tid = threadIdx.x;
    const int i = blockIdx.x * 256 + tid;
    const int v = (i < N_NODES) ? cnt[i] : 0;
    s[tid] = v;
    __syncthreads();
    for (int off = 1; off < 256; off <<= 1) {
        int x = (tid >= off) ? s[tid - off] : 0;
        __syncthreads();
        s[tid] += x;
        __syncthreads();
    }
    const int excl = part[blockIdx.x] + s[tid] - v;
    if (i <= N_NODES) ofs[i] = excl;
    if (i <  N_NODES) cursor[i] = excl;
}

__global__ __launch_bounds__(256)
void csr_fill(const int* __restrict__ col, int* __restrict__ cursor,
              int* __restrict__ eid) {
    const int i = blockIdx.x * 256 + threadIdx.x;
    if (i < N_EDGES) {
        const int p = atomicAdd(&cursor[col[i]], 1);
        eid[p] = i;
    }
}

// ---------------------------------------------------------------------------
// Pack edge-MLP weights into per-lane MFMA B-fragment order (bf16 hi/lo).
// Fragment map (mfma_f32_16x16x32_bf16): lane l, elem j -> B[kt*32+8*(l>>4)+j][nt*16+(l&15)]
// ---------------------------------------------------------------------------
__global__ __launch_bounds__(64)
void pack_weights(const float* __restrict__ W1, const float* __restrict__ W2,
                  ushort* __restrict__ p1h, ushort* __restrict__ p1l,
                  ushort* __restrict__ p2h, ushort* __restrict__ p2l)
{
    const int l = threadIdx.x;
    const int b = blockIdx.x;                  // 0..63: W1 tiles, 64..95: W2 tiles
    if (b < 64) {
        const int kt = b >> 3, nt = b & 7;
        const int kbase = kt * 32 + 8 * (l >> 4);
        const int n = nt * 16 + (l & 15);
#pragma unroll
        for (int j = 0; j < 8; ++j) {
            ushort hi, lo;
            split_bf16(W1[(kbase + j) * HID + n], hi, lo);
            p1h[(b * 64 + l) * 8 + j] = hi;
            p1l[(b * 64 + l) * 8 + j] = lo;
        }
    } else {
        const int u = b - 64;
        const int kt = u >> 3, nt = u & 7;
        const int kbase = kt * 32 + 8 * (l >> 4);
        const int n = nt * 16 + (l & 15);
#pragma unroll
        for (int j = 0; j < 8; ++j) {
            ushort hi, lo;
            split_bf16(W2[(kbase + j) * HID + n], hi, lo);
            p2h[(u * 64 + l) * 8 + j] = hi;
            p2l[(u * 64 + l) * 8 + j] = lo;
        }
    }
}

// ---------------------------------------------------------------------------
// Edge MLP via split-bf16 MFMA + col-sorted atomic scatter.
// 256 threads = 4 waves; 32 edges/block (taken in CSR order -> sorted dst).
// Wave w: m-half h=w&1 (16 edges), n-half nh=w>>1 (64 cols = 4 n-tiles).
// A-fragments staged fragment-linear in LDS (conflict-free b128 by construction).
// ---------------------------------------------------------------------------
__global__ __launch_bounds__(256, 4)
void edge_mfma(const float* __restrict__ hv,
               const int* __restrict__ row, const int* __restrict__ col,
               const float* __restrict__ eattr,
               const int* __restrict__ eids,
               const ushort* __restrict__ p1h, const ushort* __restrict__ p1l,
               const ushort* __restrict__ p2h, const ushort* __restrict__ p2l,
               const float* __restrict__ W1,    // for attr row (k=256)
               const float* __restrict__ b1, const float* __restrict__ b2,
               float* __restrict__ agg)
{
    __shared__ __align__(16) ushort AB[16384];  // 32KB: Ahi[0:8192) Alo[8192:16384)
                                                // later H1hi[0:4096) H1lo[4096:8192)
    __shared__ int   rows_s[32], cols_s[32];
    __shared__ float attr_s[32];

    const int tid = threadIdx.x;
    const int e0  = blockIdx.x * 32;

    if (tid < 32) {
        const int e = eids[e0 + tid];
        rows_s[tid] = row[e];
        cols_s[tid] = col[e];
        attr_s[tid] = eattr[e];
    }
    __syncthreads();

    // ---- stage A fragments: 1024 cells, cell c=(kt*2+h)*64+lane holds
    // ins[h*16+(lane&15)][kt*32+8*(lane>>4) + j] for j=0..7, split hi/lo ----
#pragma unroll
    for (int c = tid; c < 1024; c += 256) {
        const int kt   = c >> 7;
        const int rem  = c & 127;
        const int hh   = rem >> 6;
        const int lane = rem & 63;
        const int edge = hh * 16 + (lane & 15);
        const int kk   = kt * 32 + 8 * (lane >> 4);
        const int node = (kk < 128) ? rows_s[edge] : cols_s[edge];
        const float* src = &hv[(size_t)node * HID + (kk & 127)];
        short8 vh, vl;
#pragma unroll
        for (int j = 0; j < 8; ++j) {
            ushort h_, l_;
            split_bf16(src[j], h_, l_);
            vh[j] = (short)h_; vl[j] = (short)l_;
        }
        *(short8*)&AB[c * 8]        = vh;
        *(short8*)&AB[8192 + c * 8] = vl;
    }
    __syncthreads();

    const int l  = tid & 63;
    const int w  = tid >> 6;
    const int h  = w & 1;          // m-half (edges h*16..h*16+15)
    const int nh = w >> 1;         // n-half (cols nh*64..nh*64+63)
    const int gl = l >> 4;
    const int r  = l & 15;

    // ---- layer 1: K=256 via 8 k-tiles, 3 MFMAs per product (split) ----
    f32x4 acc[4] = {{0,0,0,0},{0,0,0,0},{0,0,0,0},{0,0,0,0}};
    for (int kt = 0; kt < 8; ++kt) {
        const short8 ah = *(const short8*)&AB[((kt * 2 + h) * 64 + l) * 8];
        const short8 al = *(const short8*)&AB[8192 + ((kt * 2 + h) * 64 + l) * 8];
#pragma unroll
        for (int i = 0; i < 4; ++i) {
            const int nt = nh * 4 + i;
            const short8 bh = *(const short8*)&p1h[((kt * 8 + nt) * 64 + l) * 8];
            const short8 bl = *(const short8*)&p1l[((kt * 8 + nt) * 64 + l) * 8];
            acc[i] = __builtin_amdgcn_mfma_f32_16x16x32_bf16(ah, bh, acc[i], 0, 0, 0);
            acc[i] = __builtin_amdgcn_mfma_f32_16x16x32_bf16(ah, bl, acc[i], 0, 0, 0);
            acc[i] = __builtin_amdgcn_mfma_f32_16x16x32_bf16(al, bh, acc[i], 0, 0, 0);
        }
    }
    __syncthreads();   // all A reads done; AB can be overlaid with H1

    // ---- L1 epilogue: +attr*W1[256], +b1, relu, split, write H1 frags ----
#pragma unroll
    for (int i = 0; i < 4; ++i) {
        const int ncol = nh * 64 + i * 16 + r;
        const float w256 = W1[256 * HID + ncol];
        const float bb   = b1[ncol];
        const int kt2 = ncol >> 5;
        const int g2  = (ncol >> 3) & 3;
        const int j   = ncol & 7;
#pragma unroll
        for (int q = 0; q < 4; ++q) {
            const int er = gl * 4 + q;               // edge within half
            const float a = attr_s[h * 16 + er];
            float v = fmaxf(acc[i][q] + bb + a * w256, 0.f);
            ushort hi, lo;
            split_bf16(v, hi, lo);
            const int cell = (kt2 * 2 + h) * 64 + g2 * 16 + er;
            AB[cell * 8 + j]        = hi;
            AB[4096 + cell * 8 + j] = lo;
        }
    }
    __syncthreads();

    // ---- layer 2: K=128 via 4 k-tiles ----
    f32x4 acc2[4] = {{0,0,0,0},{0,0,0,0},{0,0,0,0},{0,0,0,0}};
    for (int kt = 0; kt < 4; ++kt) {
        const short8 ah = *(const short8*)&AB[((kt * 2 + h) * 64 + l) * 8];
        const short8 al = *(const short8*)&AB[4096 + ((kt * 2 + h) * 64 + l) * 8];
#pragma unroll
        for (int i = 0; i < 4; ++i) {
            const int nt = nh * 4 + i;
            const short8 bh = *(const short8*)&p2h[((kt * 8 + nt) * 64 + l) * 8];
            const short8 bl = *(const short8*)&p2l[((kt * 8 + nt) * 64 + l) * 8];
            acc2[i] = __builtin_amdgcn_mfma_f32_16x16x32_bf16(ah, bh, acc2[i], 0, 0, 0);
            acc2[i] = __builtin_amdgcn_mfma_f32_16x16x32_bf16(ah, bl, acc2[i], 0, 0, 0);
            acc2[i] = __builtin_amdgcn_mfma_f32_16x16x32_bf16(al, bh, acc2[i], 0, 0, 0);
        }
    }

    // ---- L2 epilogue: +b2, scatter to agg (sorted dst; merge full runs) ----
    const int er0 = h * 16 + gl * 4;
    const int n0s = cols_s[er0 + 0];
    const int n1s = cols_s[er0 + 1];
    const int n2s = cols_s[er0 + 2];
    const int n3s = cols_s[er0 + 3];
#pragma unroll
    for (int i = 0; i < 4; ++i) {
        const int ncol = nh * 64 + i * 16 + r;
        const float bb = b2[ncol];
        const float v0 = acc2[i][0] + bb;
        const float v1 = acc2[i][1] + bb;
        const float v2 = acc2[i][2] + bb;
        const float v3 = acc2[i][3] + bb;
        if (n0s == n3s) {   // sorted => all four equal
            atomicAdd(&agg[(size_t)n0s * HID + ncol], v0 + v1 + v2 + v3);
        } else {
            atomicAdd(&agg[(size_t)n0s * HID + ncol], v0);
            atomicAdd(&agg[(size_t)n1s * HID + ncol], v1);
            atomicAdd(&agg[(size_t)n2s * HID + ncol], v2);
            atomicAdd(&agg[(size_t)n3s * HID + ncol], v3);
        }
    }
}

// ---------------------------------------------------------------------------
// Kernel C: node update (verbatim from measured-correct round 3)
// ---------------------------------------------------------------------------
__global__ __launch_bounds__(128)
void node_update(const float* __restrict__ hv,
                 const float* __restrict__ agg,
                 const float* __restrict__ W1, const float* __restrict__ b1,
                 const float* __restrict__ W2, const float* __restrict__ b2,
                 float* __restrict__ out)
{
    const int t  = threadIdx.x;
    const int n0 = blockIdx.x * 4;

    __shared__ float ins[4][260];
    __shared__ float h1[4][132];
    __shared__ float part[4][2][6];

#pragma unroll
    for (int n = 0; n < 4; ++n) {
        ins[n][t]       = hv[(size_t)(n0 + n) * HID + t];
        ins[n][HID + t] = agg[(size_t)(n0 + n) * HID + t];
    }
    __syncthreads();

    float acc[4] = {0.f, 0.f, 0.f, 0.f};
    for (int k = 0; k < 2 * HID; k += 4) {
        const float w0 = W1[(k + 0) * HID + t];
        const float w1 = W1[(k + 1) * HID + t];
        const float w2 = W1[(k + 2) * HID + t];
        const float w3 = W1[(k + 3) * HID + t];
#pragma unroll
        for (int n = 0; n < 4; ++n) {
            const float4 a = *(const float4*)&ins[n][k];
            acc[n] += a.x * w0 + a.y * w1 + a.z * w2 + a.w * w3;
        }
    }
    const float bb1 = b1[t];
#pragma unroll
    for (int n = 0; n < 4; ++n) h1[n][t] = fmaxf(acc[n] + bb1, 0.f);
    __syncthreads();

    float wv[6];
#pragma unroll
    for (int j = 0; j < 6; ++j) wv[j] = W2[t * OUT_DIM + j];

#pragma unroll
    for (int n = 0; n < 4; ++n) {
        const float v = h1[n][t];
        float p[6];
#pragma unroll
        for (int j = 0; j < 6; ++j) p[j] = v * wv[j];
#pragma unroll
        for (int off = 32; off > 0; off >>= 1) {
#pragma unroll
            for (int j = 0; j < 6; ++j) p[j] += __shfl_down(p[j], off);
        }
        if ((t & 63) == 0) {
#pragma unroll
            for (int j = 0; j < 6; ++j) part[n][t >> 6][j] = p[j];
        }
    }
    __syncthreads();

    if (t < 24) {
        const int n = t / 6, j = t % 6;
        out[(size_t)(n0 + n) * OUT_DIM + j] = part[n][0][j] + part[n][1][j] + b2[j];
    }
}

// ---------------------------------------------------------------------------
extern "C" void kernel_launch(void* const* d_in, const int* in_sizes, int n_in,
                              void* d_out, int out_size, void* d_ws, size_t ws_size,
                              hipStream_t stream) {
    const float* node_states = (const float*)d_in[0];
    const int*   edge_index  = (const int*)d_in[1];
    const float* edge_attr   = (const float*)d_in[2];
    const float* ne_W1 = (const float*)d_in[3];
    const float* ne_b1 = (const float*)d_in[4];
    const float* ne_W2 = (const float*)d_in[5];
    const float* ne_b2 = (const float*)d_in[6];
    const float* ee_W1 = (const float*)d_in[7];
    const float* ee_b1 = (const float*)d_in[8];
    const float* ee_W2 = (const float*)d_in[9];
    const float* ee_b2 = (const float*)d_in[10];
    const float* nu_W1 = (const float*)d_in[11];
    const float* nu_b1 = (const float*)d_in[12];
    const float* nu_W2 = (const float*)d_in[13];
    const float* nu_b2 = (const float*)d_in[14];

    const int* row = edge_index;
    const int* col = edge_index + N_EDGES;

    // workspace layout (~54.4 MB)
    float* hv     = (float*)d_ws;                        // [N,128]
    float* agg    = hv + (size_t)N_NODES * HID;          // [N,128]
    int*   cnt    = (int*)(agg + (size_t)N_NODES * HID); // [N]
    int*   ofs    = cnt + N_NODES;                       // [N+1]
    int*   cursor = ofs + (N_NODES + 1);                 // [N]
    int*   partb  = cursor + N_NODES;                    // [256]
    int*   eids   = partb + 256;                         // [E]
    ushort* p1h   = (ushort*)(((uintptr_t)(eids + N_EDGES) + 15) & ~(uintptr_t)15);
    ushort* p1l   = p1h + 32768;                         // [257->256 packed K x 128]
    ushort* p2h   = p1l + 32768;
    ushort* p2l   = p2h + 16384;

    hipMemsetAsync(agg, 0, (size_t)N_NODES * HID * sizeof(float), stream);
    hipMemsetAsync(cnt, 0, N_NODES * sizeof(int), stream);

    node_encoder<<<N_NODES / 4, 128, 0, stream>>>(
        node_states, ne_W1, ne_b1, ne_W2, ne_b2, hv);

    csr_count<<<(N_EDGES + 255) / 256, 256, 0, stream>>>(col, cnt);
    scan_part<<<SCAN_BLKS, 256, 0, stream>>>(cnt, partb);
    scan_scan<<<1, 256, 0, stream>>>(partb);
    scan_final<<<SCAN_BLKS, 256, 0, stream>>>(cnt, partb, ofs, cursor);
    csr_fill<<<(N_EDGES + 255) / 256, 256, 0, stream>>>(col, cursor, eids);

    pack_weights<<<96, 64, 0, stream>>>(ee_W1, ee_W2, p1h, p1l, p2h, p2l);

    edge_mfma<<<N_EDGES / 32, 256, 0, stream>>>(
        hv, row, col, edge_attr, eids,
        p1h, p1l, p2h, p2l, ee_W1, ee_b1, ee_b2, agg);

    node_update<<<N_NODES / 4, 128, 0, stream>>>(
        hv, agg, nu_W1, nu_b1, nu_W2, nu_b2, (float*)d_out);
}

// Round 10
// 699.400 us; speedup vs baseline: 2.3804x; 1.0312x over previous
//
#include <hip/hip_runtime.h>

#define N_NODES 50000
#define N_EDGES 600000
#define IN_DIM 9
#define HID 128
#define OUT_DIM 6
#define SCAN_BLKS ((N_NODES + 255) / 256)   // 196

typedef __attribute__((ext_vector_type(8))) short short8;
typedef __attribute__((ext_vector_type(4))) float f32x4;

// split x = hi + lo (bf16 each); hi is RNE, lo is truncated residual.
__device__ __forceinline__ void split_bf16(float x, ushort& hi, ushort& lo) {
    unsigned u = __float_as_uint(x);
    unsigned r = u + 0x7FFF + ((u >> 16) & 1);
    hi = (ushort)(r >> 16);
    float hif = __uint_as_float((unsigned)hi << 16);
    lo = (ushort)(__float_as_uint(x - hif) >> 16);
}

// ---------------------------------------------------------------------------
// Kernel A: node encoder -> hv pre-split into bf16 hi/lo planes.
// h_v = relu(x @ W1 + b1) @ W2 + b2   [N,9]->[N,128]
// ---------------------------------------------------------------------------
__global__ __launch_bounds__(128)
void node_encoder(const float* __restrict__ x,
                  const float* __restrict__ W1, const float* __restrict__ b1,
                  const float* __restrict__ W2, const float* __restrict__ b2,
                  ushort* __restrict__ hvh, ushort* __restrict__ hvl)
{
    const int t  = threadIdx.x;
    const int n0 = blockIdx.x * 4;

    __shared__ float xs[4][12];
    __shared__ float h1[4][132];

    if (t < 4 * IN_DIM) {
        int n = t / IN_DIM, k = t % IN_DIM;
        xs[n][k] = x[(n0 + n) * IN_DIM + k];
    }
    __syncthreads();

    float w[IN_DIM];
#pragma unroll
    for (int k = 0; k < IN_DIM; ++k) w[k] = W1[k * HID + t];
    const float bb1 = b1[t];
#pragma unroll
    for (int n = 0; n < 4; ++n) {
        float s = bb1;
#pragma unroll
        for (int k = 0; k < IN_DIM; ++k) s += xs[n][k] * w[k];
        h1[n][t] = fmaxf(s, 0.f);
    }
    __syncthreads();

    float acc[4] = {0.f, 0.f, 0.f, 0.f};
    for (int k = 0; k < HID; k += 4) {
        const float w0 = W2[(k + 0) * HID + t];
        const float w1 = W2[(k + 1) * HID + t];
        const float w2 = W2[(k + 2) * HID + t];
        const float w3 = W2[(k + 3) * HID + t];
#pragma unroll
        for (int n = 0; n < 4; ++n) {
            const float4 a = *(const float4*)&h1[n][k];
            acc[n] += a.x * w0 + a.y * w1 + a.z * w2 + a.w * w3;
        }
    }
    const float bb2 = b2[t];
#pragma unroll
    for (int n = 0; n < 4; ++n) {
        ushort hi, lo;
        split_bf16(acc[n] + bb2, hi, lo);
        hvh[(size_t)(n0 + n) * HID + t] = hi;
        hvl[(size_t)(n0 + n) * HID + t] = lo;
    }
}

// ---------------------------------------------------------------------------
// CSR build (verbatim, measured-correct): col -> edge list
// ---------------------------------------------------------------------------
__global__ __launch_bounds__(256)
void csr_count(const int* __restrict__ col, int* __restrict__ cnt) {
    const int i = blockIdx.x * 256 + threadIdx.x;
    if (i < N_EDGES) atomicAdd(&cnt[col[i]], 1);
}

__global__ __launch_bounds__(256)
void scan_part(const int* __restrict__ cnt, int* __restrict__ part) {
    __shared__ int s[256];
    const int tid = threadIdx.x;
    const int i = blockIdx.x * 256 + tid;
    s[tid] = (i < N_NODES) ? cnt[i] : 0;
    __syncthreads();
#pragma unroll
    for (int off = 128; off > 0; off >>= 1) {
        if (tid < off) s[tid] += s[tid + off];
        __syncthreads();
    }
    if (tid == 0) part[blockIdx.x] = s[0];
}

__global__ __launch_bounds__(256)
void scan_scan(int* __restrict__ part) {
    __shared__ int s[256];
    const int tid = threadIdx.x;
    const int v = (tid < SCAN_BLKS) ? part[tid] : 0;
    s[tid] = v;
    __syncthreads();
    for (int off = 1; off < 256; off <<= 1) {
        int x = (tid >= off) ? s[tid - off] : 0;
        __syncthreads();
        s[tid] += x;
        __syncthreads();
    }
    part[tid] = s[tid] - v;
}

__global__ __launch_bounds__(256)
void scan_final(const int* __restrict__ cnt, const int* __restrict__ part,
                int* __restrict__ ofs, int* __restrict__ cursor) {
    __shared__ int s[256];
    const int tid = threadIdx.x;
    const int i = blockIdx.x * 256 + tid;
    const int v = (i < N_NODES) ? cnt[i] : 0;
    s[tid] = v;
    __syncthreads();
    for (int off = 1; off < 256; off <<= 1) {
        int x = (tid >= off) ? s[tid - off] : 0;
        __syncthreads();
        s[tid] += x;
        __syncthreads();
    }
    const int excl = part[blockIdx.x] + s[tid] - v;
    if (i <= N_NODES) ofs[i] = excl;
    if (i <  N_NODES) cursor[i] = excl;
}

__global__ __launch_bounds__(256)
void csr_fill(const int* __restrict__ col, int* __restrict__ cursor,
              int* __restrict__ eid) {
    const int i = blockIdx.x * 256 + threadIdx.x;
    if (i < N_EDGES) {
        const int p = atomicAdd(&cursor[col[i]], 1);
        eid[p] = i;
    }
}

// ---------------------------------------------------------------------------
// Pack edge-MLP weights into per-lane MFMA B-fragment order (bf16 hi/lo).
// ---------------------------------------------------------------------------
__global__ __launch_bounds__(64)
void pack_weights(const float* __restrict__ W1, const float* __restrict__ W2,
                  ushort* __restrict__ p1h, ushort* __restrict__ p1l,
                  ushort* __restrict__ p2h, ushort* __restrict__ p2l)
{
    const int l = threadIdx.x;
    const int b = blockIdx.x;
    if (b < 64) {
        const int kt = b >> 3, nt = b & 7;
        const int kbase = kt * 32 + 8 * (l >> 4);
        const int n = nt * 16 + (l & 15);
#pragma unroll
        for (int j = 0; j < 8; ++j) {
            ushort hi, lo;
            split_bf16(W1[(kbase + j) * HID + n], hi, lo);
            p1h[(b * 64 + l) * 8 + j] = hi;
            p1l[(b * 64 + l) * 8 + j] = lo;
        }
    } else {
        const int u = b - 64;
        const int kt = u >> 3, nt = u & 7;
        const int kbase = kt * 32 + 8 * (l >> 4);
        const int n = nt * 16 + (l & 15);
#pragma unroll
        for (int j = 0; j < 8; ++j) {
            ushort hi, lo;
            split_bf16(W2[(kbase + j) * HID + n], hi, lo);
            p2h[(u * 64 + l) * 8 + j] = hi;
            p2l[(u * 64 + l) * 8 + j] = lo;
        }
    }
}

// ---------------------------------------------------------------------------
// Edge MLP via split-bf16 MFMA, v2: A-fragments gathered DIRECTLY from
// pre-split hv_h/hv_l (no LDS A-stage, no split VALU in hot path).
// LDS only holds the H1 inter-wave transpose (16KB) + metadata -> 8 blocks/CU.
// 256 threads = 4 waves; 32 edges/block in CSR order (sorted dst scatter).
// ---------------------------------------------------------------------------
__global__ __launch_bounds__(256, 8)
void edge_mfma(const ushort* __restrict__ hvh, const ushort* __restrict__ hvl,
               const int* __restrict__ row, const int* __restrict__ col,
               const float* __restrict__ eattr,
               const int* __restrict__ eids,
               const ushort* __restrict__ p1h, const ushort* __restrict__ p1l,
               const ushort* __restrict__ p2h, const ushort* __restrict__ p2l,
               const float* __restrict__ W1,    // for attr row (k=256)
               const float* __restrict__ b1, const float* __restrict__ b2,
               float* __restrict__ agg)
{
    __shared__ __align__(16) ushort H1h[4096];   // 8KB: layer-2 A frags (hi)
    __shared__ __align__(16) ushort H1l[4096];   // 8KB: (lo)
    __shared__ int   rows_s[32], cols_s[32];
    __shared__ float attr_s[32];

    const int tid = threadIdx.x;
    const int e0  = blockIdx.x * 32;

    if (tid < 32) {
        const int e = eids[e0 + tid];
        rows_s[tid] = row[e];
        cols_s[tid] = col[e];
        attr_s[tid] = eattr[e];
    }
    __syncthreads();

    const int l  = tid & 63;
    const int w  = tid >> 6;
    const int h  = w & 1;          // m-half (edges h*16..h*16+15)
    const int nh = w >> 1;         // n-half (cols nh*64..nh*64+63)
    const int gl = l >> 4;
    const int r  = l & 15;

    // per-lane A-gather bases: lane handles edge h*16+r, k-group gl
    const int edge  = h * 16 + r;
    const int rbyte = rows_s[edge] * 256 + gl * 16;   // 128 ushort = 256B rows
    const int cbyte = cols_s[edge] * 256 + gl * 16;

    // ---- layer 1: K=256 via 8 k-tiles; A from global, 3 MFMAs per product ----
    f32x4 acc[4] = {{0,0,0,0},{0,0,0,0},{0,0,0,0},{0,0,0,0}};
#pragma unroll
    for (int kt = 0; kt < 8; ++kt) {
        const int off = (kt < 4) ? (rbyte + kt * 64) : (cbyte + (kt - 4) * 64);
        const short8 ah = *(const short8*)((const char*)hvh + off);
        const short8 al = *(const short8*)((const char*)hvl + off);
#pragma unroll
        for (int i = 0; i < 4; ++i) {
            const int nt = nh * 4 + i;
            const short8 bh = *(const short8*)&p1h[((kt * 8 + nt) * 64 + l) * 8];
            const short8 bl = *(const short8*)&p1l[((kt * 8 + nt) * 64 + l) * 8];
            acc[i] = __builtin_amdgcn_mfma_f32_16x16x32_bf16(ah, bh, acc[i], 0, 0, 0);
            acc[i] = __builtin_amdgcn_mfma_f32_16x16x32_bf16(ah, bl, acc[i], 0, 0, 0);
            acc[i] = __builtin_amdgcn_mfma_f32_16x16x32_bf16(al, bh, acc[i], 0, 0, 0);
        }
    }

    // ---- L1 epilogue: +attr*W1[256], +b1, relu, split, write H1 frags ----
#pragma unroll
    for (int i = 0; i < 4; ++i) {
        const int ncol = nh * 64 + i * 16 + r;
        const float w256 = W1[256 * HID + ncol];
        const float bb   = b1[ncol];
        const int kt2 = ncol >> 5;
        const int g2  = (ncol >> 3) & 3;
        const int j   = ncol & 7;
#pragma unroll
        for (int q = 0; q < 4; ++q) {
            const int er = gl * 4 + q;               // edge within half
            const float a = attr_s[h * 16 + er];
            float v = fmaxf(acc[i][q] + bb + a * w256, 0.f);
            ushort hi, lo;
            split_bf16(v, hi, lo);
            const int cell = (kt2 * 2 + h) * 64 + g2 * 16 + er;
            H1h[cell * 8 + j] = hi;
            H1l[cell * 8 + j] = lo;
        }
    }
    __syncthreads();

    // ---- layer 2: K=128 via 4 k-tiles, A frags from LDS ----
    f32x4 acc2[4] = {{0,0,0,0},{0,0,0,0},{0,0,0,0},{0,0,0,0}};
#pragma unroll
    for (int kt = 0; kt < 4; ++kt) {
        const short8 ah = *(const short8*)&H1h[((kt * 2 + h) * 64 + l) * 8];
        const short8 al = *(const short8*)&H1l[((kt * 2 + h) * 64 + l) * 8];
#pragma unroll
        for (int i = 0; i < 4; ++i) {
            const int nt = nh * 4 + i;
            const short8 bh = *(const short8*)&p2h[((kt * 8 + nt) * 64 + l) * 8];
            const short8 bl = *(const short8*)&p2l[((kt * 8 + nt) * 64 + l) * 8];
            acc2[i] = __builtin_amdgcn_mfma_f32_16x16x32_bf16(ah, bh, acc2[i], 0, 0, 0);
            acc2[i] = __builtin_amdgcn_mfma_f32_16x16x32_bf16(ah, bl, acc2[i], 0, 0, 0);
            acc2[i] = __builtin_amdgcn_mfma_f32_16x16x32_bf16(al, bh, acc2[i], 0, 0, 0);
        }
    }

    // ---- L2 epilogue: +b2, scatter to agg (sorted dst; merge full runs) ----
    const int er0 = h * 16 + gl * 4;
    const int n0s = cols_s[er0 + 0];
    const int n1s = cols_s[er0 + 1];
    const int n2s = cols_s[er0 + 2];
    const int n3s = cols_s[er0 + 3];
#pragma unroll
    for (int i = 0; i < 4; ++i) {
        const int ncol = nh * 64 + i * 16 + r;
        const float bb = b2[ncol];
        const float v0 = acc2[i][0] + bb;
        const float v1 = acc2[i][1] + bb;
        const float v2 = acc2[i][2] + bb;
        const float v3 = acc2[i][3] + bb;
        if (n0s == n3s) {   // sorted => all four equal
            atomicAdd(&agg[(size_t)n0s * HID + ncol], v0 + v1 + v2 + v3);
        } else {
            atomicAdd(&agg[(size_t)n0s * HID + ncol], v0);
            atomicAdd(&agg[(size_t)n1s * HID + ncol], v1);
            atomicAdd(&agg[(size_t)n2s * HID + ncol], v2);
            atomicAdd(&agg[(size_t)n3s * HID + ncol], v3);
        }
    }
}

// ---------------------------------------------------------------------------
// Kernel C: node update (hv reconstructed from hi/lo planes; agg fp32)
// ---------------------------------------------------------------------------
__global__ __launch_bounds__(128)
void node_update(const ushort* __restrict__ hvh, const ushort* __restrict__ hvl,
                 const float* __restrict__ agg,
                 const float* __restrict__ W1, const float* __restrict__ b1,
                 const float* __restrict__ W2, const float* __restrict__ b2,
                 float* __restrict__ out)
{
    const int t  = threadIdx.x;
    const int n0 = blockIdx.x * 4;

    __shared__ float ins[4][260];
    __shared__ float h1[4][132];
    __shared__ float part[4][2][6];

#pragma unroll
    for (int n = 0; n < 4; ++n) {
        const unsigned hh = hvh[(size_t)(n0 + n) * HID + t];
        const unsigned ll = hvl[(size_t)(n0 + n) * HID + t];
        ins[n][t]       = __uint_as_float(hh << 16) + __uint_as_float(ll << 16);
        ins[n][HID + t] = agg[(size_t)(n0 + n) * HID + t];
    }
    __syncthreads();

    float acc[4] = {0.f, 0.f, 0.f, 0.f};
    for (int k = 0; k < 2 * HID; k += 4) {
        const float w0 = W1[(k + 0) * HID + t];
        const float w1 = W1[(k + 1) * HID + t];
        const float w2 = W1[(k + 2) * HID + t];
        const float w3 = W1[(k + 3) * HID + t];
#pragma unroll
        for (int n = 0; n < 4; ++n) {
            const float4 a = *(const float4*)&ins[n][k];
            acc[n] += a.x * w0 + a.y * w1 + a.z * w2 + a.w * w3;
        }
    }
    const float bb1 = b1[t];
#pragma unroll
    for (int n = 0; n < 4; ++n) h1[n][t] = fmaxf(acc[n] + bb1, 0.f);
    __syncthreads();

    float wv[6];
#pragma unroll
    for (int j = 0; j < 6; ++j) wv[j] = W2[t * OUT_DIM + j];

#pragma unroll
    for (int n = 0; n < 4; ++n) {
        const float v = h1[n][t];
        float p[6];
#pragma unroll
        for (int j = 0; j < 6; ++j) p[j] = v * wv[j];
#pragma unroll
        for (int off = 32; off > 0; off >>= 1) {
#pragma unroll
            for (int j = 0; j < 6; ++j) p[j] += __shfl_down(p[j], off);
        }
        if ((t & 63) == 0) {
#pragma unroll
            for (int j = 0; j < 6; ++j) part[n][t >> 6][j] = p[j];
        }
    }
    __syncthreads();

    if (t < 24) {
        const int n = t / 6, j = t % 6;
        out[(size_t)(n0 + n) * OUT_DIM + j] = part[n][0][j] + part[n][1][j] + b2[j];
    }
}

// ---------------------------------------------------------------------------
extern "C" void kernel_launch(void* const* d_in, const int* in_sizes, int n_in,
                              void* d_out, int out_size, void* d_ws, size_t ws_size,
                              hipStream_t stream) {
    const float* node_states = (const float*)d_in[0];
    const int*   edge_index  = (const int*)d_in[1];
    const float* edge_attr   = (const float*)d_in[2];
    const float* ne_W1 = (const float*)d_in[3];
    const float* ne_b1 = (const float*)d_in[4];
    const float* ne_W2 = (const float*)d_in[5];
    const float* ne_b2 = (const float*)d_in[6];
    const float* ee_W1 = (const float*)d_in[7];
    const float* ee_b1 = (const float*)d_in[8];
    const float* ee_W2 = (const float*)d_in[9];
    const float* ee_b2 = (const float*)d_in[10];
    const float* nu_W1 = (const float*)d_in[11];
    const float* nu_b1 = (const float*)d_in[12];
    const float* nu_W2 = (const float*)d_in[13];
    const float* nu_b2 = (const float*)d_in[14];

    const int* row = edge_index;
    const int* col = edge_index + N_EDGES;

    // workspace layout (~55 MB)
    ushort* hvh   = (ushort*)d_ws;                        // [N,128] hi  12.8MB
    ushort* hvl   = hvh + (size_t)N_NODES * HID;          // [N,128] lo  12.8MB
    float*  agg   = (float*)(hvl + (size_t)N_NODES * HID);// [N,128]     25.6MB
    int*   cnt    = (int*)(agg + (size_t)N_NODES * HID);  // [N]
    int*   ofs    = cnt + N_NODES;                        // [N+1]
    int*   cursor = ofs + (N_NODES + 1);                  // [N]
    int*   partb  = cursor + N_NODES;                     // [256]
    int*   eids   = partb + 256;                          // [E]
    ushort* p1h   = (ushort*)(((uintptr_t)(eids + N_EDGES) + 15) & ~(uintptr_t)15);
    ushort* p1l   = p1h + 32768;
    ushort* p2h   = p1l + 32768;
    ushort* p2l   = p2h + 16384;

    hipMemsetAsync(agg, 0, (size_t)N_NODES * HID * sizeof(float), stream);
    hipMemsetAsync(cnt, 0, N_NODES * sizeof(int), stream);

    node_encoder<<<N_NODES / 4, 128, 0, stream>>>(
        node_states, ne_W1, ne_b1, ne_W2, ne_b2, hvh, hvl);

    csr_count<<<(N_EDGES + 255) / 256, 256, 0, stream>>>(col, cnt);
    scan_part<<<SCAN_BLKS, 256, 0, stream>>>(cnt, partb);
    scan_scan<<<1, 256, 0, stream>>>(partb);
    scan_final<<<SCAN_BLKS, 256, 0, stream>>>(cnt, partb, ofs, cursor);
    csr_fill<<<(N_EDGES + 255) / 256, 256, 0, stream>>>(col, cursor, eids);

    pack_weights<<<96, 64, 0, stream>>>(ee_W1, ee_W2, p1h, p1l, p2h, p2l);

    edge_mfma<<<N_EDGES / 32, 256, 0, stream>>>(
        hvh, hvl, row, col, edge_attr, eids,
        p1h, p1l, p2h, p2l, ee_W1, ee_b1, ee_b2, agg);

    node_update<<<N_NODES / 4, 128, 0, stream>>>(
        hvh, hvl, agg, nu_W1, nu_b1, nu_W2, nu_b2, (float*)d_out);
}

// Round 13
// 645.264 us; speedup vs baseline: 2.5801x; 1.0839x over previous
//
#include <hip/hip_runtime.h>

#define N_NODES 50000
#define N_EDGES 600000
#define IN_DIM 9
#define HID 128
#define OUT_DIM 6
#define SCAN_BLKS ((N_NODES + 255) / 256)   // 196

typedef __attribute__((ext_vector_type(8))) short short8;
typedef __attribute__((ext_vector_type(4))) float f32x4;

// split x = hi + lo (bf16 each); hi is RNE, lo is truncated residual.
__device__ __forceinline__ void split_bf16(float x, ushort& hi, ushort& lo) {
    unsigned u = __float_as_uint(x);
    unsigned r = u + 0x7FFF + ((u >> 16) & 1);
    hi = (ushort)(r >> 16);
    float hif = __uint_as_float((unsigned)hi << 16);
    lo = (ushort)(__float_as_uint(x - hif) >> 16);
}

// ---------------------------------------------------------------------------
// Kernel A: node encoder -> hv pre-split into bf16 hi/lo planes.
// ---------------------------------------------------------------------------
__global__ __launch_bounds__(128)
void node_encoder(const float* __restrict__ x,
                  const float* __restrict__ W1, const float* __restrict__ b1,
                  const float* __restrict__ W2, const float* __restrict__ b2,
                  ushort* __restrict__ hvh, ushort* __restrict__ hvl)
{
    const int t  = threadIdx.x;
    const int n0 = blockIdx.x * 4;

    __shared__ float xs[4][12];
    __shared__ float h1[4][132];

    if (t < 4 * IN_DIM) {
        int n = t / IN_DIM, k = t % IN_DIM;
        xs[n][k] = x[(n0 + n) * IN_DIM + k];
    }
    __syncthreads();

    float w[IN_DIM];
#pragma unroll
    for (int k = 0; k < IN_DIM; ++k) w[k] = W1[k * HID + t];
    const float bb1 = b1[t];
#pragma unroll
    for (int n = 0; n < 4; ++n) {
        float s = bb1;
#pragma unroll
        for (int k = 0; k < IN_DIM; ++k) s += xs[n][k] * w[k];
        h1[n][t] = fmaxf(s, 0.f);
    }
    __syncthreads();

    float acc[4] = {0.f, 0.f, 0.f, 0.f};
    for (int k = 0; k < HID; k += 4) {
        const float w0 = W2[(k + 0) * HID + t];
        const float w1 = W2[(k + 1) * HID + t];
        const float w2 = W2[(k + 2) * HID + t];
        const float w3 = W2[(k + 3) * HID + t];
#pragma unroll
        for (int n = 0; n < 4; ++n) {
            const float4 a = *(const float4*)&h1[n][k];
            acc[n] += a.x * w0 + a.y * w1 + a.z * w2 + a.w * w3;
        }
    }
    const float bb2 = b2[t];
#pragma unroll
    for (int n = 0; n < 4; ++n) {
        ushort hi, lo;
        split_bf16(acc[n] + bb2, hi, lo);
        hvh[(size_t)(n0 + n) * HID + t] = hi;
        hvl[(size_t)(n0 + n) * HID + t] = lo;
    }
}

// ---------------------------------------------------------------------------
// CSR build (verbatim, measured-correct): col -> edge list
// ---------------------------------------------------------------------------
__global__ __launch_bounds__(256)
void csr_count(const int* __restrict__ col, int* __restrict__ cnt) {
    const int i = blockIdx.x * 256 + threadIdx.x;
    if (i < N_EDGES) atomicAdd(&cnt[col[i]], 1);
}

__global__ __launch_bounds__(256)
void scan_part(const int* __restrict__ cnt, int* __restrict__ part) {
    __shared__ int s[256];
    const int tid = threadIdx.x;
    const int i = blockIdx.x * 256 + tid;
    s[tid] = (i < N_NODES) ? cnt[i] : 0;
    __syncthreads();
#pragma unroll
    for (int off = 128; off > 0; off >>= 1) {
        if (tid < off) s[tid] += s[tid + off];
        __syncthreads();
    }
    if (tid == 0) part[blockIdx.x] = s[0];
}

__global__ __launch_bounds__(256)
void scan_scan(int* __restrict__ part) {
    __shared__ int s[256];
    const int tid = threadIdx.x;
    const int v = (tid < SCAN_BLKS) ? part[tid] : 0;
    s[tid] = v;
    __syncthreads();
    for (int off = 1; off < 256; off <<= 1) {
        int x = (tid >= off) ? s[tid - off] : 0;
        __syncthreads();
        s[tid] += x;
        __syncthreads();
    }
    part[tid] = s[tid] - v;
}

__global__ __launch_bounds__(256)
void scan_final(const int* __restrict__ cnt, const int* __restrict__ part,
                int* __restrict__ ofs, int* __restrict__ cursor) {
    __shared__ int s[256];
    const int tid = threadIdx.x;
    const int i = blockIdx.x * 256 + tid;
    const int v = (i < N_NODES) ? cnt[i] : 0;
    s[tid] = v;
    __syncthreads();
    for (int off = 1; off < 256; off <<= 1) {
        int x = (tid >= off) ? s[tid - off] : 0;
        __syncthreads();
        s[tid] += x;
        __syncthreads();
    }
    const int excl = part[blockIdx.x] + s[tid] - v;
    if (i <= N_NODES) ofs[i] = excl;
    if (i <  N_NODES) cursor[i] = excl;
}

__global__ __launch_bounds__(256)
void csr_fill(const int* __restrict__ col, int* __restrict__ cursor,
              int* __restrict__ eid) {
    const int i = blockIdx.x * 256 + threadIdx.x;
    if (i < N_EDGES) {
        const int p = atomicAdd(&cursor[col[i]], 1);
        eid[p] = i;
    }
}

// ---------------------------------------------------------------------------
// Pack edge-MLP weights into per-lane MFMA B-fragment order (bf16 hi/lo).
// ---------------------------------------------------------------------------
__global__ __launch_bounds__(64)
void pack_weights(const float* __restrict__ W1, const float* __restrict__ W2,
                  ushort* __restrict__ p1h, ushort* __restrict__ p1l,
                  ushort* __restrict__ p2h, ushort* __restrict__ p2l)
{
    const int l = threadIdx.x;
    const int b = blockIdx.x;
    if (b < 64) {
        const int kt = b >> 3, nt = b & 7;
        const int kbase = kt * 32 + 8 * (l >> 4);
        const int n = nt * 16 + (l & 15);
#pragma unroll
        for (int j = 0; j < 8; ++j) {
            ushort hi, lo;
            split_bf16(W1[(kbase + j) * HID + n], hi, lo);
            p1h[(b * 64 + l) * 8 + j] = hi;
            p1l[(b * 64 + l) * 8 + j] = lo;
        }
    } else {
        const int u = b - 64;
        const int kt = u >> 3, nt = u & 7;
        const int kbase = kt * 32 + 8 * (l >> 4);
        const int n = nt * 16 + (l & 15);
#pragma unroll
        for (int j = 0; j < 8; ++j) {
            ushort hi, lo;
            split_bf16(W2[(kbase + j) * HID + n], hi, lo);
            p2h[(u * 64 + l) * 8 + j] = hi;
            p2l[(u * 64 + l) * 8 + j] = lo;
        }
    }
}

// ---------------------------------------------------------------------------
// Edge MLP via split-bf16 MFMA, v3: 64 edges/block, each wave computes
// ALL 64 edges (4 m-tiles) x its own 32 cols (2 n-tiles).
// Per k-tile: 12 VMEM loads feed 24 MFMAs (was 10:12) -> weight traffic
// per edge drops 12 KB -> 3 KB. H1 transpose via 32 KB LDS; 4 blocks/CU.
// ---------------------------------------------------------------------------
__global__ __launch_bounds__(256, 4)
void edge_mfma(const ushort* __restrict__ hvh, const ushort* __restrict__ hvl,
               const int* __restrict__ row, const int* __restrict__ col,
               const float* __restrict__ eattr,
               const int* __restrict__ eids,
               const ushort* __restrict__ p1h, const ushort* __restrict__ p1l,
               const ushort* __restrict__ p2h, const ushort* __restrict__ p2l,
               const float* __restrict__ W1,    // for attr row (k=256)
               const float* __restrict__ b1, const float* __restrict__ b2,
               float* __restrict__ agg)
{
    __shared__ __align__(16) ushort H1h[8192];   // 16KB: layer-2 A frags (hi)
    __shared__ __align__(16) ushort H1l[8192];   // 16KB: (lo)
    __shared__ int   rows_s[64], cols_s[64];
    __shared__ float attr_s[64];

    const int tid = threadIdx.x;
    const int e0  = blockIdx.x * 64;

    if (tid < 64) {
        const int e = eids[e0 + tid];
        rows_s[tid] = row[e];
        cols_s[tid] = col[e];
        attr_s[tid] = eattr[e];
    }
    __syncthreads();

    const int l  = tid & 63;
    const int w  = tid >> 6;       // wave 0..3 owns cols w*32 .. w*32+31
    const int gl = l >> 4;         // k-group within fragment
    const int r  = l & 15;         // A: row-in-tile / B,C: col-in-tile

    // per-m-tile A gather bases (byte offsets; 256B per hv row)
    int abase[4][2];
#pragma unroll
    for (int mt = 0; mt < 4; ++mt) {
        const int el = mt * 16 + r;
        abase[mt][0] = rows_s[el] * 256 + gl * 16;
        abase[mt][1] = cols_s[el] * 256 + gl * 16;
    }

    // ---- layer 1: K=256 via 8 k-tiles; 12 loads -> 24 MFMAs per kt ----
    f32x4 acc[4][2] = {};
#pragma unroll
    for (int kt = 0; kt < 8; ++kt) {
        const int sel = kt >> 2;             // 0: row-endpoint, 1: col-endpoint
        const int ko  = (kt & 3) * 64;       // byte offset within 256B row
        short8 ah[4], al[4];
#pragma unroll
        for (int mt = 0; mt < 4; ++mt) {
            const int off = abase[mt][sel] + ko;
            ah[mt] = *(const short8*)((const char*)hvh + off);
            al[mt] = *(const short8*)((const char*)hvl + off);
        }
#pragma unroll
        for (int i = 0; i < 2; ++i) {
            const int nt = w * 2 + i;
            const short8 bh = *(const short8*)&p1h[((kt * 8 + nt) * 64 + l) * 8];
            const short8 bl = *(const short8*)&p1l[((kt * 8 + nt) * 64 + l) * 8];
#pragma unroll
            for (int mt = 0; mt < 4; ++mt) {
                acc[mt][i] = __builtin_amdgcn_mfma_f32_16x16x32_bf16(ah[mt], bh, acc[mt][i], 0, 0, 0);
                acc[mt][i] = __builtin_amdgcn_mfma_f32_16x16x32_bf16(ah[mt], bl, acc[mt][i], 0, 0, 0);
                acc[mt][i] = __builtin_amdgcn_mfma_f32_16x16x32_bf16(al[mt], bh, acc[mt][i], 0, 0, 0);
            }
        }
    }

    // ---- L1 epilogue: +attr*W1[256], +b1, relu, split, write H1 frags ----
#pragma unroll
    for (int i = 0; i < 2; ++i) {
        const int ncol = w * 32 + i * 16 + r;
        const float w256 = W1[256 * HID + ncol];
        const float bb   = b1[ncol];
        const int kt2 = ncol >> 5;
        const int gg  = (ncol >> 3) & 3;
        const int j   = ncol & 7;
#pragma unroll
        for (int mt = 0; mt < 4; ++mt) {
#pragma unroll
            for (int q = 0; q < 4; ++q) {
                const int el = mt * 16 + gl * 4 + q;     // edge within block
                float v = fmaxf(acc[mt][i][q] + bb + attr_s[el] * w256, 0.f);
                ushort hi, lo;
                split_bf16(v, hi, lo);
                const int cell = (kt2 * 4 + mt) * 64 + gg * 16 + (gl * 4 + q);
                H1h[cell * 8 + j] = hi;
                H1l[cell * 8 + j] = lo;
            }
        }
    }
    __syncthreads();

    // ---- layer 2: K=128 via 4 k-tiles; A frags from LDS ----
    f32x4 acc2[4][2] = {};
#pragma unroll
    for (int kt = 0; kt < 4; ++kt) {
        short8 ah[4], al[4];
#pragma unroll
        for (int mt = 0; mt < 4; ++mt) {
            ah[mt] = *(const short8*)&H1h[((kt * 4 + mt) * 64 + l) * 8];
            al[mt] = *(const short8*)&H1l[((kt * 4 + mt) * 64 + l) * 8];
        }
#pragma unroll
        for (int i = 0; i < 2; ++i) {
            const int nt = w * 2 + i;
            const short8 bh = *(const short8*)&p2h[((kt * 8 + nt) * 64 + l) * 8];
            const short8 bl = *(const short8*)&p2l[((kt * 8 + nt) * 64 + l) * 8];
#pragma unroll
            for (int mt = 0; mt < 4; ++mt) {
                acc2[mt][i] = __builtin_amdgcn_mfma_f32_16x16x32_bf16(ah[mt], bh, acc2[mt][i], 0, 0, 0);
                acc2[mt][i] = __builtin_amdgcn_mfma_f32_16x16x32_bf16(ah[mt], bl, acc2[mt][i], 0, 0, 0);
                acc2[mt][i] = __builtin_amdgcn_mfma_f32_16x16x32_bf16(al[mt], bh, acc2[mt][i], 0, 0, 0);
            }
        }
    }

    // ---- L2 epilogue: +b2, scatter to agg (sorted dst; merge full runs) ----
#pragma unroll
    for (int mt = 0; mt < 4; ++mt) {
        const int er0 = mt * 16 + gl * 4;
        const int n0s = cols_s[er0 + 0];
        const int n3s = cols_s[er0 + 3];
        const int n1s = cols_s[er0 + 1];
        const int n2s = cols_s[er0 + 2];
#pragma unroll
        for (int i = 0; i < 2; ++i) {
            const int ncol = w * 32 + i * 16 + r;
            const float bb = b2[ncol];
            const float v0 = acc2[mt][i][0] + bb;
            const float v1 = acc2[mt][i][1] + bb;
            const float v2 = acc2[mt][i][2] + bb;
            const float v3 = acc2[mt][i][3] + bb;
            if (n0s == n3s) {   // sorted => all four equal
                atomicAdd(&agg[(size_t)n0s * HID + ncol], v0 + v1 + v2 + v3);
            } else {
                atomicAdd(&agg[(size_t)n0s * HID + ncol], v0);
                atomicAdd(&agg[(size_t)n1s * HID + ncol], v1);
                atomicAdd(&agg[(size_t)n2s * HID + ncol], v2);
                atomicAdd(&agg[(size_t)n3s * HID + ncol], v3);
            }
        }
    }
}

// ---------------------------------------------------------------------------
// Kernel C: node update (hv reconstructed from hi/lo planes; agg fp32)
// ---------------------------------------------------------------------------
__global__ __launch_bounds__(128)
void node_update(const ushort* __restrict__ hvh, const ushort* __restrict__ hvl,
                 const float* __restrict__ agg,
                 const float* __restrict__ W1, const float* __restrict__ b1,
                 const float* __restrict__ W2, const float* __restrict__ b2,
                 float* __restrict__ out)
{
    const int t  = threadIdx.x;
    const int n0 = blockIdx.x * 4;

    __shared__ float ins[4][260];
    __shared__ float h1[4][132];
    __shared__ float part[4][2][6];

#pragma unroll
    for (int n = 0; n < 4; ++n) {
        const unsigned hh = hvh[(size_t)(n0 + n) * HID + t];
        const unsigned ll = hvl[(size_t)(n0 + n) * HID + t];
        ins[n][t]       = __uint_as_float(hh << 16) + __uint_as_float(ll << 16);
        ins[n][HID + t] = agg[(size_t)(n0 + n) * HID + t];
    }
    __syncthreads();

    float acc[4] = {0.f, 0.f, 0.f, 0.f};
    for (int k = 0; k < 2 * HID; k += 4) {
        const float w0 = W1[(k + 0) * HID + t];
        const float w1 = W1[(k + 1) * HID + t];
        const float w2 = W1[(k + 2) * HID + t];
        const float w3 = W1[(k + 3) * HID + t];
#pragma unroll
        for (int n = 0; n < 4; ++n) {
            const float4 a = *(const float4*)&ins[n][k];
            acc[n] += a.x * w0 + a.y * w1 + a.z * w2 + a.w * w3;
        }
    }
    const float bb1 = b1[t];
#pragma unroll
    for (int n = 0; n < 4; ++n) h1[n][t] = fmaxf(acc[n] + bb1, 0.f);
    __syncthreads();

    float wv[6];
#pragma unroll
    for (int j = 0; j < 6; ++j) wv[j] = W2[t * OUT_DIM + j];

#pragma unroll
    for (int n = 0; n < 4; ++n) {
        const float v = h1[n][t];
        float p[6];
#pragma unroll
        for (int j = 0; j < 6; ++j) p[j] = v * wv[j];
#pragma unroll
        for (int off = 32; off > 0; off >>= 1) {
#pragma unroll
            for (int j = 0; j < 6; ++j) p[j] += __shfl_down(p[j], off);
        }
        if ((t & 63) == 0) {
#pragma unroll
            for (int j = 0; j < 6; ++j) part[n][t >> 6][j] = p[j];
        }
    }
    __syncthreads();

    if (t < 24) {
        const int n = t / 6, j = t % 6;
        out[(size_t)(n0 + n) * OUT_DIM + j] = part[n][0][j] + part[n][1][j] + b2[j];
    }
}

// ---------------------------------------------------------------------------
extern "C" void kernel_launch(void* const* d_in, const int* in_sizes, int n_in,
                              void* d_out, int out_size, void* d_ws, size_t ws_size,
                              hipStream_t stream) {
    const float* node_states = (const float*)d_in[0];
    const int*   edge_index  = (const int*)d_in[1];
    const float* edge_attr   = (const float*)d_in[2];
    const float* ne_W1 = (const float*)d_in[3];
    const float* ne_b1 = (const float*)d_in[4];
    const float* ne_W2 = (const float*)d_in[5];
    const float* ne_b2 = (const float*)d_in[6];
    const float* ee_W1 = (const float*)d_in[7];
    const float* ee_b1 = (const float*)d_in[8];
    const float* ee_W2 = (const float*)d_in[9];
    const float* ee_b2 = (const float*)d_in[10];
    const float* nu_W1 = (const float*)d_in[11];
    const float* nu_b1 = (const float*)d_in[12];
    const float* nu_W2 = (const float*)d_in[13];
    const float* nu_b2 = (const float*)d_in[14];

    const int* row = edge_index;
    const int* col = edge_index + N_EDGES;

    // workspace layout (~55 MB)
    ushort* hvh   = (ushort*)d_ws;                        // [N,128] hi  12.8MB
    ushort* hvl   = hvh + (size_t)N_NODES * HID;          // [N,128] lo  12.8MB
    float*  agg   = (float*)(hvl + (size_t)N_NODES * HID);// [N,128]     25.6MB
    int*   cnt    = (int*)(agg + (size_t)N_NODES * HID);  // [N]
    int*   ofs    = cnt + N_NODES;                        // [N+1]
    int*   cursor = ofs + (N_NODES + 1);                  // [N]
    int*   partb  = cursor + N_NODES;                     // [256]
    int*   eids   = partb + 256;                          // [E]
    ushort* p1h   = (ushort*)(((uintptr_t)(eids + N_EDGES) + 15) & ~(uintptr_t)15);
    ushort* p1l   = p1h + 32768;
    ushort* p2h   = p1l + 32768;
    ushort* p2l   = p2h + 16384;

    hipMemsetAsync(agg, 0, (size_t)N_NODES * HID * sizeof(float), stream);
    hipMemsetAsync(cnt, 0, N_NODES * sizeof(int), stream);

    node_encoder<<<N_NODES / 4, 128, 0, stream>>>(
        node_states, ne_W1, ne_b1, ne_W2, ne_b2, hvh, hvl);

    csr_count<<<(N_EDGES + 255) / 256, 256, 0, stream>>>(col, cnt);
    scan_part<<<SCAN_BLKS, 256, 0, stream>>>(cnt, partb);
    scan_scan<<<1, 256, 0, stream>>>(partb);
    scan_final<<<SCAN_BLKS, 256, 0, stream>>>(cnt, partb, ofs, cursor);
    csr_fill<<<(N_EDGES + 255) / 256, 256, 0, stream>>>(col, cursor, eids);

    pack_weights<<<96, 64, 0, stream>>>(ee_W1, ee_W2, p1h, p1l, p2h, p2l);

    edge_mfma<<<N_EDGES / 64, 256, 0, stream>>>(
        hvh, hvl, row, col, edge_attr, eids,
        p1h, p1l, p2h, p2l, ee_W1, ee_b1, ee_b2, agg);

    node_update<<<N_NODES / 4, 128, 0, stream>>>(
        hvh, hvl, agg, nu_W1, nu_b1, nu_W2, nu_b2, (float*)d_out);
}